// Round 3
// baseline (994.520 us; speedup 1.0000x reference)
//
#include <hip/hip_runtime.h>

typedef unsigned short u16;
typedef short bf16x8 __attribute__((ext_vector_type(8)));
typedef float f32x4 __attribute__((ext_vector_type(4)));

#define S_LEN 2048
#define ATT_SCALE 0.08838834764831845f
#define NEG_BIG  -1.0e30f

static __device__ __forceinline__ float bf2f(u16 u) {
  union { unsigned int i; float f; } v; v.i = ((unsigned int)u) << 16; return v.f;
}
static __device__ __forceinline__ u16 f2bf(float f) {
  union { float f; unsigned int i; } v; v.f = f;
  unsigned int x = v.i;
  return (u16)((x + 0x7fffu + ((x >> 16) & 1u)) >> 16);  // RNE
}

// 8-element loader -> bf16x8 (fp32 source converts, bf16 source passes through)
static __device__ __forceinline__ bf16x8 load8(const u16* p) {
  return *(const bf16x8*)p;
}
static __device__ __forceinline__ bf16x8 load8(const float* p) {
  f32x4 a = *(const f32x4*)p;
  f32x4 b = *(const f32x4*)(p + 4);
  bf16x8 r;
  r[0] = (short)f2bf(a[0]); r[1] = (short)f2bf(a[1]);
  r[2] = (short)f2bf(a[2]); r[3] = (short)f2bf(a[3]);
  r[4] = (short)f2bf(b[0]); r[5] = (short)f2bf(b[1]);
  r[6] = (short)f2bf(b[2]); r[7] = (short)f2bf(b[3]);
  return r;
}
static __device__ __forceinline__ void store_out(u16* C, size_t i, float v)  { C[i] = f2bf(v); }
static __device__ __forceinline__ void store_out(float* C, size_t i, float v){ C[i] = v; }

// ---------------------------------------------------------------------------
// GEMM: C(M,N) = A(M,K) * B(N,K)^T. fp32 or bf16 inputs (converted to bf16
// in LDS staging), fp32 MFMA accum, fp32 or bf16 output.
// 128x128 tile, BK=64, 4 waves 2x2, each wave 64x64 via 4x4 MFMA tiles.
// ---------------------------------------------------------------------------
#define BM 128
#define BN 128
#define BK 64
#define LDK 72   // +8 pad

template <typename AT, typename BT, typename OT>
__global__ __launch_bounds__(256) void gemm_bt(
    const AT* __restrict__ A, const BT* __restrict__ B,
    OT* __restrict__ C, int M, int N, int K) {
  __shared__ __align__(16) u16 As[BM * LDK];
  __shared__ __align__(16) u16 Bs[BN * LDK];
  const int tid  = threadIdx.x;
  const int lane = tid & 63;
  const int wave = tid >> 6;
  const int wm = (wave >> 1) << 6;
  const int wn = (wave & 1) << 6;
  const int col  = lane & 15;
  const int quad = lane >> 4;
  const int bm = blockIdx.y * BM;
  const int bn = blockIdx.x * BN;

  const f32x4 fzero = {0.f, 0.f, 0.f, 0.f};
  f32x4 acc[4][4];
#pragma unroll
  for (int i = 0; i < 4; ++i)
#pragma unroll
    for (int j = 0; j < 4; ++j) acc[i][j] = fzero;

  const int sr = tid >> 3;         // staging row 0..31 (+32p)
  const int sc = (tid & 7) * 8;    // staging col (elements)
  const AT* Aptr = A + (size_t)(bm + sr) * K + sc;
  const BT* Bptr = B + (size_t)(bn + sr) * K + sc;

  for (int k0 = 0; k0 < K; k0 += BK) {
#pragma unroll
    for (int p = 0; p < 4; ++p) {
      *(bf16x8*)&As[(sr + 32 * p) * LDK + sc] = load8(Aptr + (size_t)(32 * p) * K + k0);
      *(bf16x8*)&Bs[(sr + 32 * p) * LDK + sc] = load8(Bptr + (size_t)(32 * p) * K + k0);
    }
    __syncthreads();
#pragma unroll
    for (int kk = 0; kk < BK; kk += 32) {
      bf16x8 af[4], bfr[4];
#pragma unroll
      for (int mt = 0; mt < 4; ++mt)
        af[mt] = *(const bf16x8*)&As[(wm + mt * 16 + col) * LDK + kk + quad * 8];
#pragma unroll
      for (int nt = 0; nt < 4; ++nt)
        bfr[nt] = *(const bf16x8*)&Bs[(wn + nt * 16 + col) * LDK + kk + quad * 8];
#pragma unroll
      for (int mt = 0; mt < 4; ++mt)
#pragma unroll
        for (int nt = 0; nt < 4; ++nt)
          acc[mt][nt] = __builtin_amdgcn_mfma_f32_16x16x32_bf16(
              af[mt], bfr[nt], acc[mt][nt], 0, 0, 0);
    }
    __syncthreads();
  }
#pragma unroll
  for (int mt = 0; mt < 4; ++mt)
#pragma unroll
    for (int nt = 0; nt < 4; ++nt)
#pragma unroll
      for (int r = 0; r < 4; ++r) {
        int row = bm + wm + mt * 16 + quad * 4 + r;
        int cn  = bn + wn + nt * 16 + col;
        store_out(C, (size_t)row * N + cn, acc[mt][nt][r]);
      }
}

// ---------------------------------------------------------------------------
// RoPE in place on q (S,32,128) and k (S,8,128) bf16; scale folded into q.
// freqs are fp32.
// ---------------------------------------------------------------------------
__global__ __launch_bounds__(256) void rope_kernel(
    u16* __restrict__ q, u16* __restrict__ k,
    const float* __restrict__ cs, const float* __restrict__ sn) {
  int idx = blockIdx.x * 256 + threadIdx.x;
  const int QP = S_LEN * 32 * 64;  // q pairs
  u16* base;
  int s, i;
  bool isq = idx < QP;
  if (isq) {
    s = idx >> 11; int w = idx & 2047; i = w & 63;
    base = q + (size_t)s * 4096 + (w >> 6) * 128 + 2 * i;
  } else {
    int j = idx - QP;
    s = j >> 9; int w = j & 511; i = w & 63;
    base = k + (size_t)s * 1024 + (w >> 6) * 128 + 2 * i;
  }
  float c  = cs[s * 64 + i];
  float sv = sn[s * 64 + i];
  float x0 = bf2f(base[0]);
  float x1 = bf2f(base[1]);
  float r0 = x0 * c - x1 * sv;
  float r1 = x0 * sv + x1 * c;
  if (isq) { r0 *= ATT_SCALE; r1 *= ATT_SCALE; }
  base[0] = f2bf(r0);
  base[1] = f2bf(r1);
}

// ---------------------------------------------------------------------------
// Causal GQA flash attention. Block = (64 q-rows, 1 head), 4 waves x 16 rows.
// KV chunks of 32. Q pre-scaled. All bf16 (workspace tensors).
// ---------------------------------------------------------------------------
__global__ __launch_bounds__(256) void attn_kernel(
    const u16* __restrict__ Q, const u16* __restrict__ K,
    const u16* __restrict__ V, u16* __restrict__ O) {
  const int qb   = 31 - blockIdx.x;  // heavy blocks first
  const int h    = blockIdx.y;
  const int kvh  = h >> 2;
  const int tid  = threadIdx.x;
  const int lane = tid & 63;
  const int wave = tid >> 6;
  const int col  = lane & 15;
  const int quad = lane >> 4;

  __shared__ __align__(16) u16 Ks[32 * 136];   // [pos][hd], pad 8
  __shared__ __align__(16) u16 Vt[128 * 40];   // [hd][pos], pad 8
  __shared__ __align__(16) u16 Pl[4][16 * 40]; // per-wave P [m][k], pad 8

  const int qrow = qb * 64 + wave * 16 + col;
  bf16x8 qf[4];
#pragma unroll
  for (int kb = 0; kb < 4; ++kb)
    qf[kb] = *(const bf16x8*)&Q[(size_t)qrow * 4096 + h * 128 + kb * 32 + quad * 8];

  const f32x4 fzero = {0.f, 0.f, 0.f, 0.f};
  f32x4 oacc[8];
#pragma unroll
  for (int nt = 0; nt < 8; ++nt) oacc[nt] = fzero;
  float mrow[4], lrow[4];
#pragma unroll
  for (int r = 0; r < 4; ++r) { mrow[r] = NEG_BIG; lrow[r] = 0.f; }

  const int sr = tid >> 4;         // 0..15
  const int sc = (tid & 15) * 8;   // 0..120
  const int rot = tid & 7;
  const int nchunk = 2 * (qb + 1);

  for (int c = 0; c < nchunk; ++c) {
    const int pos0 = c * 32;
#pragma unroll
    for (int p = 0; p < 2; ++p) {
      int r = sr + 16 * p;
      *(bf16x8*)&Ks[r * 136 + sc] =
          *(const bf16x8*)&K[(size_t)(pos0 + r) * 1024 + kvh * 128 + sc];
      union { bf16x8 v; u16 e[8]; } tmp;
      tmp.v = *(const bf16x8*)&V[(size_t)(pos0 + r) * 1024 + kvh * 128 + sc];
#pragma unroll
      for (int j = 0; j < 8; ++j) {
        int jj = (j + rot) & 7;
        Vt[(sc + jj) * 40 + r] = tmp.e[jj];
      }
    }
    __syncthreads();

    f32x4 sv[2];
    sv[0] = fzero; sv[1] = fzero;
#pragma unroll
    for (int t = 0; t < 2; ++t)
#pragma unroll
      for (int kb = 0; kb < 4; ++kb) {
        bf16x8 kf = *(const bf16x8*)&Ks[(t * 16 + col) * 136 + kb * 32 + quad * 8];
        sv[t] = __builtin_amdgcn_mfma_f32_16x16x32_bf16(qf[kb], kf, sv[t], 0, 0, 0);
      }

#pragma unroll
    for (int r = 0; r < 4; ++r) {
      const int qpos = qb * 64 + wave * 16 + quad * 4 + r;
      float s0 = (pos0 + col)      <= qpos ? sv[0][r] : NEG_BIG;
      float s1 = (pos0 + 16 + col) <= qpos ? sv[1][r] : NEG_BIG;
      float mx = fmaxf(s0, s1);
#pragma unroll
      for (int d = 1; d < 16; d <<= 1) mx = fmaxf(mx, __shfl_xor(mx, d));
      float mnew  = fmaxf(mrow[r], mx);
      float alpha = __expf(mrow[r] - mnew);
      float p0 = __expf(s0 - mnew);
      float p1 = __expf(s1 - mnew);
      float ls = p0 + p1;
#pragma unroll
      for (int d = 1; d < 16; d <<= 1) ls += __shfl_xor(ls, d);
      lrow[r] = lrow[r] * alpha + ls;
      mrow[r] = mnew;
#pragma unroll
      for (int nt = 0; nt < 8; ++nt) oacc[nt][r] *= alpha;
      Pl[wave][(quad * 4 + r) * 40 + col]      = f2bf(p0);
      Pl[wave][(quad * 4 + r) * 40 + 16 + col] = f2bf(p1);
    }
    __syncthreads();

    bf16x8 pa = *(const bf16x8*)&Pl[wave][col * 40 + quad * 8];
#pragma unroll
    for (int nt = 0; nt < 8; ++nt) {
      bf16x8 vf = *(const bf16x8*)&Vt[(nt * 16 + col) * 40 + quad * 8];
      oacc[nt] = __builtin_amdgcn_mfma_f32_16x16x32_bf16(pa, vf, oacc[nt], 0, 0, 0);
    }
    __syncthreads();
  }

#pragma unroll
  for (int r = 0; r < 4; ++r) {
    float inv = 1.f / lrow[r];
    const int row = qb * 64 + wave * 16 + quad * 4 + r;
#pragma unroll
    for (int nt = 0; nt < 8; ++nt)
      O[(size_t)row * 4096 + h * 128 + nt * 16 + col] = f2bf(oacc[nt][r] * inv);
  }
}

// ---------------------------------------------------------------------------
extern "C" void kernel_launch(void* const* d_in, const int* in_sizes, int n_in,
                              void* d_out, int out_size, void* d_ws, size_t ws_size,
                              hipStream_t stream) {
  const float* x  = (const float*)d_in[0];
  const float* fc = (const float*)d_in[1];
  const float* fs = (const float*)d_in[2];
  const float* wq = (const float*)d_in[3];
  const float* wk = (const float*)d_in[4];
  const float* wv = (const float*)d_in[5];
  const float* wo = (const float*)d_in[6];
  float* out = (float*)d_out;

  u16* q  = (u16*)d_ws;                      // 2048*4096 bf16
  u16* k  = q + (size_t)2048 * 4096;         // 2048*1024 bf16
  u16* v  = k + (size_t)2048 * 1024;         // 2048*1024 bf16
  u16* ao = v + (size_t)2048 * 1024;         // 2048*4096 bf16

  dim3 blk(256, 1, 1);
  hipLaunchKernelGGL((gemm_bt<float, float, u16>), dim3(32, 16, 1), blk, 0, stream,
                     x, wq, q, 2048, 4096, 4096);
  hipLaunchKernelGGL((gemm_bt<float, float, u16>), dim3(8, 16, 1),  blk, 0, stream,
                     x, wk, k, 2048, 1024, 4096);
  hipLaunchKernelGGL((gemm_bt<float, float, u16>), dim3(8, 16, 1),  blk, 0, stream,
                     x, wv, v, 2048, 1024, 4096);
  hipLaunchKernelGGL(rope_kernel, dim3(20480, 1, 1), blk, 0, stream, q, k, fc, fs);
  hipLaunchKernelGGL(attn_kernel, dim3(32, 32, 1), blk, 0, stream, q, k, v, ao);
  hipLaunchKernelGGL((gemm_bt<u16, float, float>), dim3(32, 16, 1), blk, 0, stream,
                     ao, wo, out, 2048, 4096, 4096);
}

// Round 4
// 694.341 us; speedup vs baseline: 1.4323x; 1.4323x over previous
//
#include <hip/hip_runtime.h>

typedef unsigned short u16;
typedef short bf16x8 __attribute__((ext_vector_type(8)));
typedef float f32x4 __attribute__((ext_vector_type(4)));

#define S_LEN 2048
#define ATT_SCALE 0.08838834764831845f
#define NEG_BIG  -1.0e30f

static __device__ __forceinline__ float bf2f(u16 u) {
  union { unsigned int i; float f; } v; v.i = ((unsigned int)u) << 16; return v.f;
}
static __device__ __forceinline__ u16 f2bf(float f) {
  union { float f; unsigned int i; } v; v.f = f;
  unsigned int x = v.i;
  return (u16)((x + 0x7fffu + ((x >> 16) & 1u)) >> 16);  // RNE
}

// async global->LDS, 16B per lane; lds dest = wave-uniform base + lane*16
static __device__ __forceinline__ void gl_lds16(const u16* g, u16* l) {
  __builtin_amdgcn_global_load_lds(
      (const __attribute__((address_space(1))) unsigned int*)g,
      (__attribute__((address_space(3))) unsigned int*)l, 16, 0, 0);
}

static __device__ __forceinline__ bf16x8 load8(const u16* p) { return *(const bf16x8*)p; }
static __device__ __forceinline__ bf16x8 load8(const float* p) {
  f32x4 a = *(const f32x4*)p;
  f32x4 b = *(const f32x4*)(p + 4);
  bf16x8 r;
  r[0] = (short)f2bf(a[0]); r[1] = (short)f2bf(a[1]);
  r[2] = (short)f2bf(a[2]); r[3] = (short)f2bf(a[3]);
  r[4] = (short)f2bf(b[0]); r[5] = (short)f2bf(b[1]);
  r[6] = (short)f2bf(b[2]); r[7] = (short)f2bf(b[3]);
  return r;
}
static __device__ __forceinline__ void store_out(u16* C, size_t i, float v)  { C[i] = f2bf(v); }
static __device__ __forceinline__ void store_out(float* C, size_t i, float v){ C[i] = v; }

// ---------------------------------------------------------------------------
// fp32 -> bf16 bulk convert (8 elems/thread)
// ---------------------------------------------------------------------------
__global__ __launch_bounds__(256) void f2b_kernel(
    const float* __restrict__ s, u16* __restrict__ d, int n8) {
  int i = blockIdx.x * 256 + threadIdx.x;
  if (i >= n8) return;
  *(bf16x8*)&d[(size_t)i * 8] = load8(s + (size_t)i * 8);
}

// ---------------------------------------------------------------------------
// m97-style bf16 GEMM core: C(M,N) = A(M,K)*B(N,K)^T.
// 128x128 tile, BK=64. global_load_lds width-16 staging into UNPADDED
// XOR-swizzled LDS: slot (row, c) holds global k-chunk (c ^ (row&7)).
// Fragment reads then hit all 32 banks 2-way (free).
// ---------------------------------------------------------------------------
template <typename OT>
static __device__ __forceinline__ void gemm_core(
    const u16* __restrict__ A, const u16* __restrict__ B, OT* __restrict__ C,
    int K, int ldc, int bm, int bn) {
  __shared__ __align__(16) u16 As[128 * 64];
  __shared__ __align__(16) u16 Bs[128 * 64];
  const int tid  = threadIdx.x;
  const int lane = tid & 63;
  const int wave = tid >> 6;
  const int wm = (wave >> 1) << 6;
  const int wn = (wave & 1) << 6;
  const int col  = lane & 15;
  const int quad = lane >> 4;

  const f32x4 fzero = {0.f, 0.f, 0.f, 0.f};
  f32x4 acc[4][4];
#pragma unroll
  for (int i = 0; i < 4; ++i)
#pragma unroll
    for (int j = 0; j < 4; ++j) acc[i][j] = fzero;

  const int srow = (lane >> 3);       // row within 8-row issue
  const int sc8  = lane & 7;          // LDS chunk slot 0..7

  for (int k0 = 0; k0 < K; k0 += 64) {
#pragma unroll
    for (int i = 0; i < 4; ++i) {
      int r = wave * 32 + i * 8 + srow;
      int src = (sc8 ^ (r & 7)) << 3;
      gl_lds16(A + (size_t)(bm + r) * K + k0 + src, &As[(wave * 32 + i * 8) * 64]);
      gl_lds16(B + (size_t)(bn + r) * K + k0 + src, &Bs[(wave * 32 + i * 8) * 64]);
    }
    __syncthreads();
#pragma unroll
    for (int kk = 0; kk < 64; kk += 32) {
      bf16x8 af[4], bfr[4];
#pragma unroll
      for (int mt = 0; mt < 4; ++mt) {
        int row = wm + mt * 16 + col;
        af[mt] = *(const bf16x8*)&As[row * 64 + ((((kk >> 3) + quad) ^ (col & 7)) << 3)];
      }
#pragma unroll
      for (int nt = 0; nt < 4; ++nt) {
        int row = wn + nt * 16 + col;
        bfr[nt] = *(const bf16x8*)&Bs[row * 64 + ((((kk >> 3) + quad) ^ (col & 7)) << 3)];
      }
#pragma unroll
      for (int mt = 0; mt < 4; ++mt)
#pragma unroll
        for (int nt = 0; nt < 4; ++nt)
          acc[mt][nt] = __builtin_amdgcn_mfma_f32_16x16x32_bf16(
              af[mt], bfr[nt], acc[mt][nt], 0, 0, 0);
    }
    __syncthreads();
  }
#pragma unroll
  for (int mt = 0; mt < 4; ++mt)
#pragma unroll
    for (int nt = 0; nt < 4; ++nt)
#pragma unroll
      for (int r = 0; r < 4; ++r) {
        int row = bm + wm + mt * 16 + quad * 4 + r;
        int cn  = bn + wn + nt * 16 + col;
        store_out(C, (size_t)row * ldc + cn, acc[mt][nt][r]);
      }
}

// Fused QKV projection: x(2048,4096) x {wq,wk,wv}^T -> q,k,v
__global__ __launch_bounds__(256) void gemm_qkv(
    const u16* __restrict__ xb, const u16* __restrict__ wqb,
    const u16* __restrict__ wkb, const u16* __restrict__ wvb,
    u16* __restrict__ q, u16* __restrict__ k, u16* __restrict__ v) {
  int bx = blockIdx.x;
  const u16* B; u16* C; int ldc, bn;
  if (bx < 32)      { B = wqb; C = q; ldc = 4096; bn = bx * 128; }
  else if (bx < 40) { B = wkb; C = k; ldc = 1024; bn = (bx - 32) * 128; }
  else              { B = wvb; C = v; ldc = 1024; bn = (bx - 40) * 128; }
  gemm_core<u16>(xb, B, C, 4096, ldc, blockIdx.y * 128, bn);
}

// Output projection: ao(2048,4096) x wo^T -> out (fp32)
__global__ __launch_bounds__(256) void gemm_o(
    const u16* __restrict__ ao, const u16* __restrict__ wob, float* __restrict__ out) {
  gemm_core<float>(ao, wob, out, 4096, 4096, blockIdx.y * 128, blockIdx.x * 128);
}

// ---------------------------------------------------------------------------
// Fallback GEMM (fp32 staging convert, m93-class) for small workspace
// ---------------------------------------------------------------------------
#define LDK 72
template <typename AT, typename BT, typename OT>
__global__ __launch_bounds__(256) void gemm_bt(
    const AT* __restrict__ A, const BT* __restrict__ B,
    OT* __restrict__ C, int M, int N, int K) {
  __shared__ __align__(16) u16 As[128 * LDK];
  __shared__ __align__(16) u16 Bs[128 * LDK];
  const int tid  = threadIdx.x;
  const int lane = tid & 63;
  const int wave = tid >> 6;
  const int wm = (wave >> 1) << 6;
  const int wn = (wave & 1) << 6;
  const int col  = lane & 15;
  const int quad = lane >> 4;
  const int bm = blockIdx.y * 128;
  const int bn = blockIdx.x * 128;

  const f32x4 fzero = {0.f, 0.f, 0.f, 0.f};
  f32x4 acc[4][4];
#pragma unroll
  for (int i = 0; i < 4; ++i)
#pragma unroll
    for (int j = 0; j < 4; ++j) acc[i][j] = fzero;

  const int sr = tid >> 3;
  const int sc = (tid & 7) * 8;
  const AT* Aptr = A + (size_t)(bm + sr) * K + sc;
  const BT* Bptr = B + (size_t)(bn + sr) * K + sc;

  for (int k0 = 0; k0 < K; k0 += 64) {
#pragma unroll
    for (int p = 0; p < 4; ++p) {
      *(bf16x8*)&As[(sr + 32 * p) * LDK + sc] = load8(Aptr + (size_t)(32 * p) * K + k0);
      *(bf16x8*)&Bs[(sr + 32 * p) * LDK + sc] = load8(Bptr + (size_t)(32 * p) * K + k0);
    }
    __syncthreads();
#pragma unroll
    for (int kk = 0; kk < 64; kk += 32) {
      bf16x8 af[4], bfr[4];
#pragma unroll
      for (int mt = 0; mt < 4; ++mt)
        af[mt] = *(const bf16x8*)&As[(wm + mt * 16 + col) * LDK + kk + quad * 8];
#pragma unroll
      for (int nt = 0; nt < 4; ++nt)
        bfr[nt] = *(const bf16x8*)&Bs[(wn + nt * 16 + col) * LDK + kk + quad * 8];
#pragma unroll
      for (int mt = 0; mt < 4; ++mt)
#pragma unroll
        for (int nt = 0; nt < 4; ++nt)
          acc[mt][nt] = __builtin_amdgcn_mfma_f32_16x16x32_bf16(
              af[mt], bfr[nt], acc[mt][nt], 0, 0, 0);
    }
    __syncthreads();
  }
#pragma unroll
  for (int mt = 0; mt < 4; ++mt)
#pragma unroll
    for (int nt = 0; nt < 4; ++nt)
#pragma unroll
      for (int r = 0; r < 4; ++r) {
        int row = bm + wm + mt * 16 + quad * 4 + r;
        int cn  = bn + wn + nt * 16 + col;
        store_out(C, (size_t)row * N + cn, acc[mt][nt][r]);
      }
}

// ---------------------------------------------------------------------------
// RoPE in place on q (S,32,128) and k (S,8,128) bf16; scale folded into q.
// ---------------------------------------------------------------------------
__global__ __launch_bounds__(256) void rope_kernel(
    u16* __restrict__ q, u16* __restrict__ k,
    const float* __restrict__ cs, const float* __restrict__ sn) {
  int idx = blockIdx.x * 256 + threadIdx.x;
  const int QP = S_LEN * 32 * 64;
  u16* base;
  int s, i;
  bool isq = idx < QP;
  if (isq) {
    s = idx >> 11; int w = idx & 2047; i = w & 63;
    base = q + (size_t)s * 4096 + (w >> 6) * 128 + 2 * i;
  } else {
    int j = idx - QP;
    s = j >> 9; int w = j & 511; i = w & 63;
    base = k + (size_t)s * 1024 + (w >> 6) * 128 + 2 * i;
  }
  float c  = cs[s * 64 + i];
  float sv = sn[s * 64 + i];
  float x0 = bf2f(base[0]);
  float x1 = bf2f(base[1]);
  float r0 = x0 * c - x1 * sv;
  float r1 = x0 * sv + x1 * c;
  if (isq) { r0 *= ATT_SCALE; r1 *= ATT_SCALE; }
  base[0] = f2bf(r0);
  base[1] = f2bf(r1);
}

// ---------------------------------------------------------------------------
// Causal GQA flash attention, v2.
// Block = (32 q-rows, KV-group); 4 waves = the 4 heads sharing K/V.
// KV chunk = 64. LDS tiles unpadded + XOR-swizzled on 16B chunks:
//   slot(row, c) holds global chunk (c ^ (row&7)) -> all frag reads 2-way/free.
// K staged via global_load_lds; V transposed with packed b32 writes (free banks).
// ---------------------------------------------------------------------------
__global__ __launch_bounds__(256) void attn_kernel(
    const u16* __restrict__ Q, const u16* __restrict__ K,
    const u16* __restrict__ V, u16* __restrict__ O) {
  const int qb   = 63 - blockIdx.x;  // heavy blocks first
  const int g    = blockIdx.y;       // kv group
  const int tid  = threadIdx.x;
  const int lane = tid & 63;
  const int wave = tid >> 6;
  const int h    = g * 4 + wave;
  const int col  = lane & 15;
  const int quad = lane >> 4;

  __shared__ __align__(16) u16 Ks[64 * 128];    // [pos][hd], hd-chunks swizzled
  __shared__ __align__(16) u16 Vt[128 * 64];    // [hd][pos], pos-chunks swizzled
  __shared__ __align__(16) u16 Pl[4][32 * 64];  // per-wave P[m][pos], swizzled

  // Q A-fragments in registers
  bf16x8 qf[2][4];
#pragma unroll
  for (int mt = 0; mt < 2; ++mt)
#pragma unroll
    for (int kb = 0; kb < 4; ++kb)
      qf[mt][kb] = *(const bf16x8*)
          &Q[(size_t)(qb * 32 + mt * 16 + col) * 4096 + h * 128 + kb * 32 + quad * 8];

  const f32x4 fzero = {0.f, 0.f, 0.f, 0.f};
  f32x4 oacc[2][8];
#pragma unroll
  for (int mt = 0; mt < 2; ++mt)
#pragma unroll
    for (int nt = 0; nt < 8; ++nt) oacc[mt][nt] = fzero;
  float m_[2][4], l_[2][4];
#pragma unroll
  for (int mt = 0; mt < 2; ++mt)
#pragma unroll
    for (int r = 0; r < 4; ++r) { m_[mt][r] = NEG_BIG; l_[mt][r] = 0.f; }

  // staging indices
  const int krow = lane >> 4;        // K: row within 4-row issue
  const int kcnk = lane & 15;        // K: chunk slot 0..15
  const int vsc  = (tid & 15) * 8;   // V: hd group base
  const int vrp  = tid >> 4;         // V: pos-pair 0..15
  const int vrot = tid & 7;

  const int nchunk = (qb + 2) >> 1;
  for (int c = 0; c < nchunk; ++c) {
    const int pos0 = c * 64;
    // ---- stage K via global_load_lds (rows wave*16 .. wave*16+15)
#pragma unroll
    for (int i = 0; i < 4; ++i) {
      int r = wave * 16 + i * 4 + krow;
      int src = ((kcnk & 8) | ((kcnk ^ r) & 7)) << 3;
      gl_lds16(&K[(size_t)(pos0 + r) * 1024 + g * 128 + src], &Ks[(wave * 16 + i * 4) * 128]);
    }
    // ---- stage V^T: packed pos-pairs, swizzled chunks
#pragma unroll
    for (int it = 0; it < 2; ++it) {
      int rp = vrp + it * 16;        // pos-pair 0..31
      const u16* vp = &V[(size_t)(pos0 + 2 * rp) * 1024 + g * 128 + vsc];
      union { bf16x8 v; u16 u[8]; } ue, uo;
      ue.v = *(const bf16x8*)vp;
      uo.v = *(const bf16x8*)(vp + 1024);
      int pc = rp >> 2, pi = rp & 3;
#pragma unroll
      for (int j = 0; j < 8; ++j) {
        int jj = (j + vrot) & 7;
        int hd = vsc + jj;
        unsigned val = (unsigned)ue.u[jj] | ((unsigned)uo.u[jj] << 16);
        *(unsigned*)&Vt[hd * 64 + ((pc ^ (hd & 7)) << 3) + pi * 2] = val;
      }
    }
    __syncthreads();

    // ---- S = Q K^T : 2 m-tiles x 4 kv-tiles per wave
    f32x4 sv[2][4];
#pragma unroll
    for (int mt = 0; mt < 2; ++mt)
#pragma unroll
      for (int kv = 0; kv < 4; ++kv) sv[mt][kv] = fzero;
#pragma unroll
    for (int kv = 0; kv < 4; ++kv) {
      int r = kv * 16 + col;
#pragma unroll
      for (int kb = 0; kb < 4; ++kb) {
        int kq = kb * 4 + quad;
        int slot = (kq & 8) | ((kq ^ r) & 7);
        bf16x8 kf = *(const bf16x8*)&Ks[r * 128 + slot * 8];
        sv[0][kv] = __builtin_amdgcn_mfma_f32_16x16x32_bf16(qf[0][kb], kf, sv[0][kv], 0, 0, 0);
        sv[1][kv] = __builtin_amdgcn_mfma_f32_16x16x32_bf16(qf[1][kb], kf, sv[1][kv], 0, 0, 0);
      }
    }

    // ---- online softmax + P write (swizzled)
#pragma unroll
    for (int mt = 0; mt < 2; ++mt)
#pragma unroll
      for (int r = 0; r < 4; ++r) {
        const int qpos = qb * 32 + mt * 16 + quad * 4 + r;
        float s0 = (pos0 + col)      <= qpos ? sv[mt][0][r] : NEG_BIG;
        float s1 = (pos0 + 16 + col) <= qpos ? sv[mt][1][r] : NEG_BIG;
        float s2 = (pos0 + 32 + col) <= qpos ? sv[mt][2][r] : NEG_BIG;
        float s3 = (pos0 + 48 + col) <= qpos ? sv[mt][3][r] : NEG_BIG;
        float mx = fmaxf(fmaxf(s0, s1), fmaxf(s2, s3));
#pragma unroll
        for (int d = 1; d < 16; d <<= 1) mx = fmaxf(mx, __shfl_xor(mx, d));
        float mnew  = fmaxf(m_[mt][r], mx);
        float alpha = __expf(m_[mt][r] - mnew);
        float p0 = __expf(s0 - mnew);
        float p1 = __expf(s1 - mnew);
        float p2 = __expf(s2 - mnew);
        float p3 = __expf(s3 - mnew);
        float ls = (p0 + p1) + (p2 + p3);
#pragma unroll
        for (int d = 1; d < 16; d <<= 1) ls += __shfl_xor(ls, d);
        l_[mt][r] = l_[mt][r] * alpha + ls;
        m_[mt][r] = mnew;
#pragma unroll
        for (int nt = 0; nt < 8; ++nt) oacc[mt][nt][r] *= alpha;
        int m  = mt * 16 + quad * 4 + r;
        int m7 = m & 7;
        u16* pr = &Pl[wave][m * 64];
        pr[(((0 * 2 + (col >> 3)) ^ m7) << 3) + (col & 7)] = f2bf(p0);
        pr[(((1 * 2 + (col >> 3)) ^ m7) << 3) + (col & 7)] = f2bf(p1);
        pr[(((2 * 2 + (col >> 3)) ^ m7) << 3) + (col & 7)] = f2bf(p2);
        pr[(((3 * 2 + (col >> 3)) ^ m7) << 3) + (col & 7)] = f2bf(p3);
      }
    __syncthreads();

    // ---- O += P V
#pragma unroll
    for (int kc = 0; kc < 2; ++kc) {
      int pc = kc * 4 + quad;
      bf16x8 pa[2];
#pragma unroll
      for (int mt = 0; mt < 2; ++mt) {
        int m = mt * 16 + col;
        pa[mt] = *(const bf16x8*)&Pl[wave][m * 64 + ((pc ^ (col & 7)) << 3)];
      }
#pragma unroll
      for (int nt = 0; nt < 8; ++nt) {
        int hd = nt * 16 + col;
        bf16x8 vf = *(const bf16x8*)&Vt[hd * 64 + ((pc ^ (hd & 7)) << 3)];
        oacc[0][nt] = __builtin_amdgcn_mfma_f32_16x16x32_bf16(pa[0], vf, oacc[0][nt], 0, 0, 0);
        oacc[1][nt] = __builtin_amdgcn_mfma_f32_16x16x32_bf16(pa[1], vf, oacc[1][nt], 0, 0, 0);
      }
    }
    __syncthreads();
  }

  // epilogue
#pragma unroll
  for (int mt = 0; mt < 2; ++mt)
#pragma unroll
    for (int r = 0; r < 4; ++r) {
      float inv = 1.f / l_[mt][r];
      const int row = qb * 32 + mt * 16 + quad * 4 + r;
#pragma unroll
      for (int nt = 0; nt < 8; ++nt)
        O[(size_t)row * 4096 + h * 128 + nt * 16 + col] = f2bf(oacc[mt][nt][r] * inv);
    }
}

// ---------------------------------------------------------------------------
extern "C" void kernel_launch(void* const* d_in, const int* in_sizes, int n_in,
                              void* d_out, int out_size, void* d_ws, size_t ws_size,
                              hipStream_t stream) {
  const float* x  = (const float*)d_in[0];
  const float* fc = (const float*)d_in[1];
  const float* fs = (const float*)d_in[2];
  const float* wq = (const float*)d_in[3];
  const float* wk = (const float*)d_in[4];
  const float* wv = (const float*)d_in[5];
  const float* wo = (const float*)d_in[6];
  float* out = (float*)d_out;

  u16* q  = (u16*)d_ws;                      // 2048*4096
  u16* k  = q + (size_t)8388608;             // 2048*1024
  u16* v  = k + (size_t)2097152;
  u16* ao = v + (size_t)2097152;             // 2048*4096

  dim3 blk(256, 1, 1);
  const size_t NEED_FAST = 109051904ULL;     // bytes

  if (ws_size >= NEED_FAST) {
    u16* xb  = ao  + (size_t)8388608;        // 2048*4096
    u16* wqb = xb  + (size_t)8388608;        // 4096*4096
    u16* wkb = wqb + (size_t)16777216;       // 1024*4096
    u16* wvb = wkb + (size_t)4194304;        // 1024*4096
    u16* wob = wqb;                          // reuse after QKV GEMM

    hipLaunchKernelGGL(f2b_kernel, dim3(4096, 1, 1), blk, 0, stream, x,  xb,  1048576);
    hipLaunchKernelGGL(f2b_kernel, dim3(8192, 1, 1), blk, 0, stream, wq, wqb, 2097152);
    hipLaunchKernelGGL(f2b_kernel, dim3(2048, 1, 1), blk, 0, stream, wk, wkb, 524288);
    hipLaunchKernelGGL(f2b_kernel, dim3(2048, 1, 1), blk, 0, stream, wv, wvb, 524288);
    hipLaunchKernelGGL(gemm_qkv, dim3(48, 16, 1), blk, 0, stream, xb, wqb, wkb, wvb, q, k, v);
    hipLaunchKernelGGL(f2b_kernel, dim3(8192, 1, 1), blk, 0, stream, wo, wob, 2097152);
    hipLaunchKernelGGL(rope_kernel, dim3(20480, 1, 1), blk, 0, stream, q, k, fc, fs);
    hipLaunchKernelGGL(attn_kernel, dim3(64, 8, 1), blk, 0, stream, q, k, v, ao);
    hipLaunchKernelGGL(gemm_o, dim3(32, 16, 1), blk, 0, stream, ao, wob, out);
  } else {
    hipLaunchKernelGGL((gemm_bt<float, float, u16>), dim3(32, 16, 1), blk, 0, stream,
                       x, wq, q, 2048, 4096, 4096);
    hipLaunchKernelGGL((gemm_bt<float, float, u16>), dim3(8, 16, 1),  blk, 0, stream,
                       x, wk, k, 2048, 1024, 4096);
    hipLaunchKernelGGL((gemm_bt<float, float, u16>), dim3(8, 16, 1),  blk, 0, stream,
                       x, wv, v, 2048, 1024, 4096);
    hipLaunchKernelGGL(rope_kernel, dim3(20480, 1, 1), blk, 0, stream, q, k, fc, fs);
    hipLaunchKernelGGL(attn_kernel, dim3(64, 8, 1), blk, 0, stream, q, k, v, ao);
    hipLaunchKernelGGL((gemm_bt<u16, float, float>), dim3(32, 16, 1), blk, 0, stream,
                       ao, wo, out, 2048, 4096, 4096);
  }
}

// Round 5
// 668.561 us; speedup vs baseline: 1.4876x; 1.0386x over previous
//
#include <hip/hip_runtime.h>

typedef unsigned short u16;
typedef short bf16x8 __attribute__((ext_vector_type(8)));
typedef float f32x4 __attribute__((ext_vector_type(4)));

#define S_LEN 2048
#define ATT_SCALE 0.08838834764831845f
#define NEG_BIG  -1.0e30f

static __device__ __forceinline__ float bf2f(u16 u) {
  union { unsigned int i; float f; } v; v.i = ((unsigned int)u) << 16; return v.f;
}
static __device__ __forceinline__ u16 f2bf(float f) {
  union { float f; unsigned int i; } v; v.f = f;
  unsigned int x = v.i;
  return (u16)((x + 0x7fffu + ((x >> 16) & 1u)) >> 16);  // RNE
}

// async global->LDS, 16B per lane; lds dest = wave-uniform base + lane*16
static __device__ __forceinline__ void gl_lds16(const u16* g, u16* l) {
  __builtin_amdgcn_global_load_lds(
      (const __attribute__((address_space(1))) unsigned int*)g,
      (__attribute__((address_space(3))) unsigned int*)l, 16, 0, 0);
}

static __device__ __forceinline__ bf16x8 load8(const u16* p) { return *(const bf16x8*)p; }
static __device__ __forceinline__ bf16x8 load8(const float* p) {
  f32x4 a = *(const f32x4*)p;
  f32x4 b = *(const f32x4*)(p + 4);
  bf16x8 r;
  r[0] = (short)f2bf(a[0]); r[1] = (short)f2bf(a[1]);
  r[2] = (short)f2bf(a[2]); r[3] = (short)f2bf(a[3]);
  r[4] = (short)f2bf(b[0]); r[5] = (short)f2bf(b[1]);
  r[6] = (short)f2bf(b[2]); r[7] = (short)f2bf(b[3]);
  return r;
}
static __device__ __forceinline__ void store_out(u16* C, size_t i, float v)  { C[i] = f2bf(v); }
static __device__ __forceinline__ void store_out(float* C, size_t i, float v){ C[i] = v; }

// ---------------------------------------------------------------------------
// fp32 -> bf16 bulk convert (8 elems/thread)
// ---------------------------------------------------------------------------
__global__ __launch_bounds__(256) void f2b_kernel(
    const float* __restrict__ s, u16* __restrict__ d, int n8) {
  int i = blockIdx.x * 256 + threadIdx.x;
  if (i >= n8) return;
  *(bf16x8*)&d[(size_t)i * 8] = load8(s + (size_t)i * 8);
}

// ---------------------------------------------------------------------------
// m97-style bf16 GEMM core: C(M,N) = A(M,K)*B(N,K)^T.
// 128x128 tile, BK=64, global_load_lds width-16, XOR-swizzled unpadded LDS.
// ---------------------------------------------------------------------------
template <typename OT>
static __device__ __forceinline__ void gemm_core(
    const u16* __restrict__ A, const u16* __restrict__ B, OT* __restrict__ C,
    int K, int ldc, int bm, int bn) {
  __shared__ __align__(16) u16 As[128 * 64];
  __shared__ __align__(16) u16 Bs[128 * 64];
  const int tid  = threadIdx.x;
  const int lane = tid & 63;
  const int wave = tid >> 6;
  const int wm = (wave >> 1) << 6;
  const int wn = (wave & 1) << 6;
  const int col  = lane & 15;
  const int quad = lane >> 4;

  const f32x4 fzero = {0.f, 0.f, 0.f, 0.f};
  f32x4 acc[4][4];
#pragma unroll
  for (int i = 0; i < 4; ++i)
#pragma unroll
    for (int j = 0; j < 4; ++j) acc[i][j] = fzero;

  const int srow = (lane >> 3);
  const int sc8  = lane & 7;

  for (int k0 = 0; k0 < K; k0 += 64) {
#pragma unroll
    for (int i = 0; i < 4; ++i) {
      int r = wave * 32 + i * 8 + srow;
      int src = (sc8 ^ (r & 7)) << 3;
      gl_lds16(A + (size_t)(bm + r) * K + k0 + src, &As[(wave * 32 + i * 8) * 64]);
      gl_lds16(B + (size_t)(bn + r) * K + k0 + src, &Bs[(wave * 32 + i * 8) * 64]);
    }
    __syncthreads();
#pragma unroll
    for (int kk = 0; kk < 64; kk += 32) {
      bf16x8 af[4], bfr[4];
#pragma unroll
      for (int mt = 0; mt < 4; ++mt) {
        int row = wm + mt * 16 + col;
        af[mt] = *(const bf16x8*)&As[row * 64 + ((((kk >> 3) + quad) ^ (col & 7)) << 3)];
      }
#pragma unroll
      for (int nt = 0; nt < 4; ++nt) {
        int row = wn + nt * 16 + col;
        bfr[nt] = *(const bf16x8*)&Bs[row * 64 + ((((kk >> 3) + quad) ^ (col & 7)) << 3)];
      }
#pragma unroll
      for (int mt = 0; mt < 4; ++mt)
#pragma unroll
        for (int nt = 0; nt < 4; ++nt)
          acc[mt][nt] = __builtin_amdgcn_mfma_f32_16x16x32_bf16(
              af[mt], bfr[nt], acc[mt][nt], 0, 0, 0);
    }
    __syncthreads();
  }
#pragma unroll
  for (int mt = 0; mt < 4; ++mt)
#pragma unroll
    for (int nt = 0; nt < 4; ++nt)
#pragma unroll
      for (int r = 0; r < 4; ++r) {
        int row = bm + wm + mt * 16 + quad * 4 + r;
        int cn  = bn + wn + nt * 16 + col;
        store_out(C, (size_t)row * ldc + cn, acc[mt][nt][r]);
      }
}

__global__ __launch_bounds__(256) void gemm_qkv(
    const u16* __restrict__ xb, const u16* __restrict__ wqb,
    const u16* __restrict__ wkb, const u16* __restrict__ wvb,
    u16* __restrict__ q, u16* __restrict__ k, u16* __restrict__ v) {
  int bx = blockIdx.x;
  const u16* B; u16* C; int ldc, bn;
  if (bx < 32)      { B = wqb; C = q; ldc = 4096; bn = bx * 128; }
  else if (bx < 40) { B = wkb; C = k; ldc = 1024; bn = (bx - 32) * 128; }
  else              { B = wvb; C = v; ldc = 1024; bn = (bx - 40) * 128; }
  gemm_core<u16>(xb, B, C, 4096, ldc, blockIdx.y * 128, bn);
}

__global__ __launch_bounds__(256) void gemm_o(
    const u16* __restrict__ ao, const u16* __restrict__ wob, float* __restrict__ out) {
  gemm_core<float>(ao, wob, out, 4096, 4096, blockIdx.y * 128, blockIdx.x * 128);
}

// ---------------------------------------------------------------------------
// Fallback GEMM (fp32 staging convert, m93-class) for small workspace
// ---------------------------------------------------------------------------
#define LDK 72
template <typename AT, typename BT, typename OT>
__global__ __launch_bounds__(256) void gemm_bt(
    const AT* __restrict__ A, const BT* __restrict__ B,
    OT* __restrict__ C, int M, int N, int K) {
  __shared__ __align__(16) u16 As[128 * LDK];
  __shared__ __align__(16) u16 Bs[128 * LDK];
  const int tid  = threadIdx.x;
  const int lane = tid & 63;
  const int wave = tid >> 6;
  const int wm = (wave >> 1) << 6;
  const int wn = (wave & 1) << 6;
  const int col  = lane & 15;
  const int quad = lane >> 4;
  const int bm = blockIdx.y * 128;
  const int bn = blockIdx.x * 128;

  const f32x4 fzero = {0.f, 0.f, 0.f, 0.f};
  f32x4 acc[4][4];
#pragma unroll
  for (int i = 0; i < 4; ++i)
#pragma unroll
    for (int j = 0; j < 4; ++j) acc[i][j] = fzero;

  const int sr = tid >> 3;
  const int sc = (tid & 7) * 8;
  const AT* Aptr = A + (size_t)(bm + sr) * K + sc;
  const BT* Bptr = B + (size_t)(bn + sr) * K + sc;

  for (int k0 = 0; k0 < K; k0 += 64) {
#pragma unroll
    for (int p = 0; p < 4; ++p) {
      *(bf16x8*)&As[(sr + 32 * p) * LDK + sc] = load8(Aptr + (size_t)(32 * p) * K + k0);
      *(bf16x8*)&Bs[(sr + 32 * p) * LDK + sc] = load8(Bptr + (size_t)(32 * p) * K + k0);
    }
    __syncthreads();
#pragma unroll
    for (int kk = 0; kk < 64; kk += 32) {
      bf16x8 af[4], bfr[4];
#pragma unroll
      for (int mt = 0; mt < 4; ++mt)
        af[mt] = *(const bf16x8*)&As[(wm + mt * 16 + col) * LDK + kk + quad * 8];
#pragma unroll
      for (int nt = 0; nt < 4; ++nt)
        bfr[nt] = *(const bf16x8*)&Bs[(wn + nt * 16 + col) * LDK + kk + quad * 8];
#pragma unroll
      for (int mt = 0; mt < 4; ++mt)
#pragma unroll
        for (int nt = 0; nt < 4; ++nt)
          acc[mt][nt] = __builtin_amdgcn_mfma_f32_16x16x32_bf16(
              af[mt], bfr[nt], acc[mt][nt], 0, 0, 0);
    }
    __syncthreads();
  }
#pragma unroll
  for (int mt = 0; mt < 4; ++mt)
#pragma unroll
    for (int nt = 0; nt < 4; ++nt)
#pragma unroll
      for (int r = 0; r < 4; ++r) {
        int row = bm + wm + mt * 16 + quad * 4 + r;
        int cn  = bn + wn + nt * 16 + col;
        store_out(C, (size_t)row * N + cn, acc[mt][nt][r]);
      }
}

// ---------------------------------------------------------------------------
// RoPE in place on q (S,32,128) and k (S,8,128) bf16; scale folded into q.
// ---------------------------------------------------------------------------
__global__ __launch_bounds__(256) void rope_kernel(
    u16* __restrict__ q, u16* __restrict__ k,
    const float* __restrict__ cs, const float* __restrict__ sn) {
  int idx = blockIdx.x * 256 + threadIdx.x;
  const int QP = S_LEN * 32 * 64;
  u16* base;
  int s, i;
  bool isq = idx < QP;
  if (isq) {
    s = idx >> 11; int w = idx & 2047; i = w & 63;
    base = q + (size_t)s * 4096 + (w >> 6) * 128 + 2 * i;
  } else {
    int j = idx - QP;
    s = j >> 9; int w = j & 511; i = w & 63;
    base = k + (size_t)s * 1024 + (w >> 6) * 128 + 2 * i;
  }
  float c  = cs[s * 64 + i];
  float sv = sn[s * 64 + i];
  float x0 = bf2f(base[0]);
  float x1 = bf2f(base[1]);
  float r0 = x0 * c - x1 * sv;
  float r1 = x0 * sv + x1 * c;
  if (isq) { r0 *= ATT_SCALE; r1 *= ATT_SCALE; }
  base[0] = f2bf(r0);
  base[1] = f2bf(r1);
}

// ---------------------------------------------------------------------------
// Causal GQA flash attention, v3: transposed-score layout.
// Block = (64 q-rows, 1 head), 4 waves x 16 q-rows. KV chunk 64.
// S^T = K*Q^T so each q-row's scores sit in one lane (16 regs x 4 quads):
// softmax = in-register tree + 2 shuffles. P^T -> PV B-frag via in-register
// cross-lane shuffles (no LDS round-trip, no third barrier).
// O accumulated transposed (O^T[hd][q]); fixed at epilogue.
// ---------------------------------------------------------------------------
__global__ __launch_bounds__(256, 3) void attn_kernel(
    const u16* __restrict__ Q, const u16* __restrict__ K,
    const u16* __restrict__ V, u16* __restrict__ O) {
  const int qb   = 31 - blockIdx.x;  // heavy blocks first
  const int h    = blockIdx.y;
  const int kvh  = h >> 2;
  const int tid  = threadIdx.x;
  const int lane = tid & 63;
  const int wave = tid >> 6;
  const int col  = lane & 15;
  const int quad = lane >> 4;

  __shared__ __align__(16) u16 Ks[64 * 128];  // [pos][hd], hd-chunks swizzled
  __shared__ __align__(16) u16 Vt[128 * 64];  // [hd][pos], pos-chunks swizzled

  const int qpos = qb * 64 + wave * 16 + col;

  // Q fragments (B-operand: n=q=lane&15, k=quad*8+j), 4 d-windows
  bf16x8 qf[4];
#pragma unroll
  for (int kb = 0; kb < 4; ++kb)
    qf[kb] = *(const bf16x8*)&Q[(size_t)qpos * 4096 + h * 128 + kb * 32 + quad * 8];

  const f32x4 fzero = {0.f, 0.f, 0.f, 0.f};
  // O^T accumulator: oacc[nt][r] at hd = nt*16 + quad*4 + r, q = col
  f32x4 oacc[8];
#pragma unroll
  for (int nt = 0; nt < 8; ++nt) oacc[nt] = fzero;
  float m_ = NEG_BIG, l_ = 0.f;

  // staging indices
  const int krow = lane >> 4;        // K: row within 4-row issue
  const int kcnk = lane & 15;        // K: chunk slot 0..15
  const int vsc  = (tid & 15) * 8;   // V: hd group base
  const int vrp  = tid >> 4;         // V: pos-pair 0..15 (block-wide)
  const int vrot = tid & 7;

  const int nchunk = qb + 1;
  for (int c = 0; c < nchunk; ++c) {
    const int pos0 = c * 64;
    // ---- stage K via global_load_lds: wave stages rows wave*16..+15
#pragma unroll
    for (int i = 0; i < 4; ++i) {
      int r = wave * 16 + i * 4 + krow;
      int src = ((kcnk & 8) | ((kcnk ^ r) & 7)) << 3;
      gl_lds16(&K[(size_t)(pos0 + r) * 1024 + kvh * 128 + src],
               &Ks[(wave * 16 + i * 4) * 128]);
    }
    // ---- stage V^T: packed pos-pair b32 writes, swizzled pos-chunks
#pragma unroll
    for (int it = 0; it < 2; ++it) {
      int rp = vrp + it * 16;        // pos-pair 0..31
      const u16* vp = &V[(size_t)(pos0 + 2 * rp) * 1024 + kvh * 128 + vsc];
      union { bf16x8 v; u16 u[8]; } ue, uo;
      ue.v = *(const bf16x8*)vp;
      uo.v = *(const bf16x8*)(vp + 1024);
      int pc = rp >> 2, pi = rp & 3;
#pragma unroll
      for (int j = 0; j < 8; ++j) {
        int jj = (j + vrot) & 7;
        int hd = vsc + jj;
        unsigned val = (unsigned)ue.u[jj] | ((unsigned)uo.u[jj] << 16);
        *(unsigned*)&Vt[hd * 64 + ((pc ^ (hd & 7)) << 3) + pi * 2] = val;
      }
    }
    __syncthreads();

    // ---- S^T = K Q^T : 4 kpos-tiles (m) x 1 q-tile (n) per wave
    f32x4 sv[4];
#pragma unroll
    for (int kv = 0; kv < 4; ++kv) sv[kv] = fzero;
#pragma unroll
    for (int kv = 0; kv < 4; ++kv) {
      int r = kv * 16 + col;
#pragma unroll
      for (int kb = 0; kb < 4; ++kb) {
        int kq = kb * 4 + quad;
        int slot = (kq & 8) | ((kq ^ r) & 7);
        bf16x8 kf = *(const bf16x8*)&Ks[r * 128 + slot * 8];
        sv[kv] = __builtin_amdgcn_mfma_f32_16x16x32_bf16(kf, qf[kb], sv[kv], 0, 0, 0);
      }
    }

    // ---- softmax over this lane's 16 values (q = col fixed) + quad-reduce
    float mx = NEG_BIG;
#pragma unroll
    for (int kv = 0; kv < 4; ++kv)
#pragma unroll
      for (int r = 0; r < 4; ++r) {
        float s = (pos0 + kv * 16 + quad * 4 + r) <= qpos ? sv[kv][r] : NEG_BIG;
        sv[kv][r] = s;
        mx = fmaxf(mx, s);
      }
    mx = fmaxf(mx, __shfl_xor(mx, 16));
    mx = fmaxf(mx, __shfl_xor(mx, 32));
    float mnew  = fmaxf(m_, mx);
    float alpha = __expf(m_ - mnew);
    float ls = 0.f;
#pragma unroll
    for (int kv = 0; kv < 4; ++kv)
#pragma unroll
      for (int r = 0; r < 4; ++r) {
        float p = __expf(sv[kv][r] - mnew);
        sv[kv][r] = p;
        ls += p;
      }
    ls += __shfl_xor(ls, 16);
    ls += __shfl_xor(ls, 32);
    l_ = l_ * alpha + ls;
    m_ = mnew;
#pragma unroll
    for (int nt = 0; nt < 8; ++nt) {
      oacc[nt][0] *= alpha; oacc[nt][1] *= alpha;
      oacc[nt][2] *= alpha; oacc[nt][3] *= alpha;
    }

    // pack P^T tiles: pk[kv][hh] = bf16x2(p[2hh], p[2hh+1])
    unsigned pk[4][2];
#pragma unroll
    for (int kv = 0; kv < 4; ++kv) {
      pk[kv][0] = (unsigned)f2bf(sv[kv][0]) | ((unsigned)f2bf(sv[kv][1]) << 16);
      pk[kv][1] = (unsigned)f2bf(sv[kv][2]) | ((unsigned)f2bf(sv[kv][3]) << 16);
    }

    // ---- O^T += V^T P^T, P B-frags built by in-register shuffle transpose
    const int idxA = col + 16 * (2 * (quad & 1));
    const int idxB = idxA + 16;
    const bool hi  = quad >= 2;
#pragma unroll
    for (int kc = 0; kc < 2; ++kc) {
      unsigned a00 = __shfl(pk[2 * kc][0],     idxA);
      unsigned a01 = __shfl(pk[2 * kc][1],     idxA);
      unsigned a10 = __shfl(pk[2 * kc + 1][0], idxA);
      unsigned a11 = __shfl(pk[2 * kc + 1][1], idxA);
      unsigned b00 = __shfl(pk[2 * kc][0],     idxB);
      unsigned b01 = __shfl(pk[2 * kc][1],     idxB);
      unsigned b10 = __shfl(pk[2 * kc + 1][0], idxB);
      unsigned b11 = __shfl(pk[2 * kc + 1][1], idxB);
      union { unsigned u[4]; bf16x8 v; } pb;
      pb.u[0] = hi ? a10 : a00;
      pb.u[1] = hi ? a11 : a01;
      pb.u[2] = hi ? b10 : b00;
      pb.u[3] = hi ? b11 : b01;
#pragma unroll
      for (int nt = 0; nt < 8; ++nt) {
        int hd = nt * 16 + col;
        int pc = kc * 4 + quad;
        bf16x8 vf = *(const bf16x8*)&Vt[hd * 64 + ((pc ^ (hd & 7)) << 3)];
        oacc[nt] = __builtin_amdgcn_mfma_f32_16x16x32_bf16(vf, pb.v, oacc[nt], 0, 0, 0);
      }
    }
    __syncthreads();
  }

  // epilogue: O^T -> O, 8B packed stores (4 consecutive hd per lane)
  float inv = 1.f / l_;
#pragma unroll
  for (int nt = 0; nt < 8; ++nt) {
    union { u16 u[4]; unsigned long long ll; } w;
    w.u[0] = f2bf(oacc[nt][0] * inv);
    w.u[1] = f2bf(oacc[nt][1] * inv);
    w.u[2] = f2bf(oacc[nt][2] * inv);
    w.u[3] = f2bf(oacc[nt][3] * inv);
    *(unsigned long long*)&O[(size_t)qpos * 4096 + h * 128 + nt * 16 + quad * 4] = w.ll;
  }
}

// ---------------------------------------------------------------------------
extern "C" void kernel_launch(void* const* d_in, const int* in_sizes, int n_in,
                              void* d_out, int out_size, void* d_ws, size_t ws_size,
                              hipStream_t stream) {
  const float* x  = (const float*)d_in[0];
  const float* fc = (const float*)d_in[1];
  const float* fs = (const float*)d_in[2];
  const float* wq = (const float*)d_in[3];
  const float* wk = (const float*)d_in[4];
  const float* wv = (const float*)d_in[5];
  const float* wo = (const float*)d_in[6];
  float* out = (float*)d_out;

  u16* q  = (u16*)d_ws;                      // 2048*4096
  u16* k  = q + (size_t)8388608;             // 2048*1024
  u16* v  = k + (size_t)2097152;
  u16* ao = v + (size_t)2097152;             // 2048*4096

  dim3 blk(256, 1, 1);
  const size_t NEED_FAST = 109051904ULL;     // bytes

  if (ws_size >= NEED_FAST) {
    u16* xb  = ao  + (size_t)8388608;        // 2048*4096
    u16* wqb = xb  + (size_t)8388608;        // 4096*4096
    u16* wkb = wqb + (size_t)16777216;       // 1024*4096
    u16* wvb = wkb + (size_t)4194304;        // 1024*4096
    u16* wob = wqb;                          // reuse after QKV GEMM

    hipLaunchKernelGGL(f2b_kernel, dim3(4096, 1, 1), blk, 0, stream, x,  xb,  1048576);
    hipLaunchKernelGGL(f2b_kernel, dim3(8192, 1, 1), blk, 0, stream, wq, wqb, 2097152);
    hipLaunchKernelGGL(f2b_kernel, dim3(2048, 1, 1), blk, 0, stream, wk, wkb, 524288);
    hipLaunchKernelGGL(f2b_kernel, dim3(2048, 1, 1), blk, 0, stream, wv, wvb, 524288);
    hipLaunchKernelGGL(gemm_qkv, dim3(48, 16, 1), blk, 0, stream, xb, wqb, wkb, wvb, q, k, v);
    hipLaunchKernelGGL(f2b_kernel, dim3(8192, 1, 1), blk, 0, stream, wo, wob, 2097152);
    hipLaunchKernelGGL(rope_kernel, dim3(20480, 1, 1), blk, 0, stream, q, k, fc, fs);
    hipLaunchKernelGGL(attn_kernel, dim3(32, 32, 1), blk, 0, stream, q, k, v, ao);
    hipLaunchKernelGGL(gemm_o, dim3(32, 16, 1), blk, 0, stream, ao, wob, out);
  } else {
    hipLaunchKernelGGL((gemm_bt<float, float, u16>), dim3(32, 16, 1), blk, 0, stream,
                       x, wq, q, 2048, 4096, 4096);
    hipLaunchKernelGGL((gemm_bt<float, float, u16>), dim3(8, 16, 1),  blk, 0, stream,
                       x, wk, k, 2048, 1024, 4096);
    hipLaunchKernelGGL((gemm_bt<float, float, u16>), dim3(8, 16, 1),  blk, 0, stream,
                       x, wv, v, 2048, 1024, 4096);
    hipLaunchKernelGGL(rope_kernel, dim3(20480, 1, 1), blk, 0, stream, q, k, fc, fs);
    hipLaunchKernelGGL(attn_kernel, dim3(32, 32, 1), blk, 0, stream, q, k, v, ao);
    hipLaunchKernelGGL((gemm_bt<u16, float, float>), dim3(32, 16, 1), blk, 0, stream,
                       ao, wo, out, 2048, 4096, 4096);
  }
}